// Round 7
// baseline (124.993 us; speedup 1.0000x reference)
//
#include <hip/hip_runtime.h>
#include <hip/hip_bf16.h>

#define B_   4
#define LQ_  128
#define LF_  64
#define NW_  2
#define NFR_ 8
#define E_   128
#define D_   128
#define V_   64
#define NWF_ (NW_*NFR_)            // 16

using bf16 = __hip_bfloat16;
typedef unsigned short u16;
typedef unsigned int   u32;
typedef __attribute__((ext_vector_type(8))) short  bf16x8;
typedef __attribute__((ext_vector_type(4))) float  f32x4;
typedef __attribute__((ext_vector_type(4))) u32    u32x4;

// ---- out layout (element units; u16 if BF out else f32) ----
#define OUT_FRAGCODE  0       // (B,NW,NFR,D)   8192
#define OUT_QUERYCODE 8192    // (B,NW,NFR,D)   8192
#define OUT_SELFATT   16384   // (B,NW,NFR,LF)  4096
#define OUT_QFGATE    20480   // (B,16,LQ)      8192
#define OUT_QUERY     28672   // (B,LQ,D)       65536

// ---- LDS layout (bytes) ----
#define L_FP   0        // u16 [64][128] swizzled        16384
#define L_QP   16384    // u16 [128][128] swizzled       32768
#define L_FA   49152    // u16 [64][72]                   9216
#define L_E2   58368    // f32 [128]                       512
#define L_N    58880    // f32 [128]                       512
#define L_SAW  59392    // f32 [128]                       512
#define L_ATT  59904    // f32 [64]                        256
#define L_RED  60160    // f32 [512]                      2048
#define L_PART 62208    // f32 [8]                          32
#define L_TOT  62240

__device__ __forceinline__ float us2f(u16 v) { return __uint_as_float((u32)v << 16); }
__device__ __forceinline__ float lo2f(u32 v) { return __uint_as_float(v << 16); }
__device__ __forceinline__ float hi2f(u32 v) { return __uint_as_float(v & 0xffff0000u); }
__device__ __forceinline__ u16 f2b_raw(float f) {
    u32 u = __float_as_uint(f);
    return (u16)((u + 0x7fffu + ((u >> 16) & 1u)) >> 16);
}
// truncating pack of two floats' bf16 parts into one u32 (1 v_perm)
__device__ __forceinline__ u32 pk2(float hi, float lo) {
    return __builtin_amdgcn_perm(__float_as_uint(hi), __float_as_uint(lo), 0x07060302u);
}
template<bool BF> __device__ __forceinline__ float LD(const void* p, int i) {
    return BF ? us2f(((const u16*)p)[i]) : ((const float*)p)[i];
}
template<bool BF> __device__ __forceinline__ void ST(void* p, int i, float v) {
    if (BF) ((u16*)p)[i] = f2b_raw(v); else ((float*)p)[i] = v;
}
template<bool BF> __device__ __forceinline__ u16 LDB(const void* p, int i) {
    return BF ? ((const u16*)p)[i] : f2b_raw(((const float*)p)[i]);
}
__device__ __forceinline__ bool is_bf(const void* qmask) {
    return ((const u16*)qmask)[0] == 0x3F80u;
}
// A-fragment (16 rows x 32 k) direct from a global row-major [*, 128] matrix
template<bool BF>
__device__ __forceinline__ bf16x8 loadA(const void* x, int row, int kt, int quad) {
    int off = row * 128 + kt * 32 + quad * 8;
    if (BF) return *(const bf16x8*)((const u16*)x + off);
    f32x4 a = *(const f32x4*)((const float*)x + off);
    f32x4 c = *(const f32x4*)((const float*)x + off + 4);
    u32x4 av;
    av.x = pk2(a.y, a.x); av.y = pk2(a.w, a.z);
    av.z = pk2(c.y, c.x); av.w = pk2(c.w, c.z);
    return __builtin_bit_cast(bf16x8, av);
}
// B-fragment from global [k][N] weight via 8 strided scalar loads
template<bool BF>
__device__ __forceinline__ bf16x8 ldBf(const void* W, int N, int n, int k0) {
    short tmp[8];
    #pragma unroll
    for (int j = 0; j < 8; ++j) tmp[j] = (short)LDB<BF>(W, (k0 + j) * N + n);
    bf16x8 f;
    #pragma unroll
    for (int j = 0; j < 8; ++j) f[j] = tmp[j];
    return f;
}

// ===================== the single fused kernel =============================
// 64 blocks (one per bwf) x 512 threads (8 waves). Wave w owns q-tile
// [w*16, w*16+16) across ALL 64 l and all 64 v. Waves 0-3 additionally
// project the fp tile and compute f_att for their l-quarter.
template<bool BF>
__device__ __forceinline__ void main_body(
    const void* query, const void* fragment, const void* qmask, const void* fmask,
    const void* projW, const void* projB, const void* saW, const void* qattW,
    const void* fattW, const void* qfW, const void* gatew, const void* valw,
    void* out, char* smem)
{
    u16*   s_fp   = (u16*)(smem + L_FP);
    u16*   s_qp   = (u16*)(smem + L_QP);
    u16*   s_fa   = (u16*)(smem + L_FA);
    float* s_e2   = (float*)(smem + L_E2);
    float* s_n    = (float*)(smem + L_N);
    float* s_saw  = (float*)(smem + L_SAW);
    float* s_att  = (float*)(smem + L_ATT);
    float* s_red  = (float*)(smem + L_RED);
    float* s_part = (float*)(smem + L_PART);

    int bwf = blockIdx.x, b = bwf >> 4;
    int t = threadIdx.x, lane = t & 63, w = t >> 6;
    int m = lane & 15, quad = lane >> 4;
    int sk = (m & 7) << 3;

    // ---------- P1: projection (fp by waves 0-3; qp by all 8 waves) ----------
    {
        bool dofp = (w < 4);
        bf16x8 af_q[4], af_f[4];
        #pragma unroll
        for (int kt = 0; kt < 4; ++kt)
            af_q[kt] = loadA<BF>(query, b * 128 + w * 16 + m, kt, quad);
        if (dofp)
            #pragma unroll
            for (int kt = 0; kt < 4; ++kt)
                af_f[kt] = loadA<BF>(fragment, bwf * 64 + w * 16 + m, kt, quad);
        #pragma unroll
        for (int nt = 0; nt < 8; ++nt) {
            int n = nt * 16 + m;
            bf16x8 bw[4];
            #pragma unroll
            for (int kt = 0; kt < 4; ++kt) bw[kt] = ldBf<BF>(projW, 128, n, kt * 32 + quad * 8);
            float bv = LD<BF>(projB, n);
            f32x4 aq = (f32x4){bv, bv, bv, bv};
            #pragma unroll
            for (int kt = 0; kt < 4; ++kt)
                aq = __builtin_amdgcn_mfma_f32_16x16x32_bf16(af_q[kt], bw[kt], aq, 0, 0, 0);
            #pragma unroll
            for (int rr = 0; rr < 4; ++rr) {
                int row = w * 16 + quad * 4 + rr;
                s_qp[row * 128 + (n ^ ((row & 7) << 3))] = f2b_raw(aq[rr]);
            }
            if (dofp) {
                f32x4 afc = (f32x4){bv, bv, bv, bv};
                #pragma unroll
                for (int kt = 0; kt < 4; ++kt)
                    afc = __builtin_amdgcn_mfma_f32_16x16x32_bf16(af_f[kt], bw[kt], afc, 0, 0, 0);
                #pragma unroll
                for (int rr = 0; rr < 4; ++rr) {
                    int row = w * 16 + quad * 4 + rr;
                    s_fp[row * 128 + (n ^ ((row & 7) << 3))] = f2b_raw(afc[rr]);
                }
            }
        }
    }
    __syncthreads();

    // ---------- P2: qat (regs), qpreg, w3f; f_att by waves 0-3 ----------
    bf16x8 aq2[4];
    #pragma unroll
    for (int kt = 0; kt < 4; ++kt)
        aq2[kt] = *(const bf16x8*)&s_qp[(w * 16 + m) * 128 + ((kt * 32 + quad * 8) ^ sk)];
    f32x4 qat[4];
    #pragma unroll
    for (int vt = 0; vt < 4; ++vt) {
        qat[vt] = (f32x4){0.f, 0.f, 0.f, 0.f};
        #pragma unroll
        for (int kt = 0; kt < 4; ++kt) {
            bf16x8 bb = ldBf<BF>(qattW, 64, vt * 16 + m, kt * 32 + quad * 8);
            qat[vt] = __builtin_amdgcn_mfma_f32_16x16x32_bf16(aq2[kt], bb, qat[vt], 0, 0, 0);
        }
    }
    float qpreg[4][8];
    #pragma unroll
    for (int kt = 0; kt < 4; ++kt) {
        u32x4 uv = __builtin_bit_cast(u32x4, aq2[kt]);
        qpreg[kt][0] = lo2f(uv.x); qpreg[kt][1] = hi2f(uv.x);
        qpreg[kt][2] = lo2f(uv.y); qpreg[kt][3] = hi2f(uv.y);
        qpreg[kt][4] = lo2f(uv.z); qpreg[kt][5] = hi2f(uv.z);
        qpreg[kt][6] = lo2f(uv.w); qpreg[kt][7] = hi2f(uv.w);
    }
    if (w < 4) {
        bf16x8 afa[4];
        #pragma unroll
        for (int kt = 0; kt < 4; ++kt)
            afa[kt] = *(const bf16x8*)&s_fp[(w * 16 + m) * 128 + ((kt * 32 + quad * 8) ^ sk)];
        #pragma unroll
        for (int vt = 0; vt < 4; ++vt) {
            f32x4 a0 = (f32x4){0.f, 0.f, 0.f, 0.f};
            #pragma unroll
            for (int kt = 0; kt < 4; ++kt) {
                bf16x8 wk = ldBf<BF>(fattW, 64, vt * 16 + m, kt * 32 + quad * 8);
                a0 = __builtin_amdgcn_mfma_f32_16x16x32_bf16(afa[kt], wk, a0, 0, 0, 0);
            }
            #pragma unroll
            for (int r = 0; r < 4; ++r)
                s_fa[(w * 16 + quad * 4 + r) * 72 + vt * 16 + m] = f2b_raw(a0[r]);
        }
    }
    bf16x8 w3f[4][4];
    #pragma unroll
    for (int vt = 0; vt < 4; ++vt)
        #pragma unroll
        for (int kt = 0; kt < 4; ++kt)
            w3f[vt][kt] = ldBf<BF>(qfW, 64, vt * 16 + m, kt * 32 + quad * 8);
    __syncthreads();

    // ---------- P3: the l-loop (all 64 l, this wave's 16 q, all 4 vt) ----------
    float mx[4][4];
    #pragma unroll
    for (int vt = 0; vt < 4; ++vt)
        #pragma unroll
        for (int r = 0; r < 4; ++r) mx[vt][r] = -1e30f;
    #pragma unroll 2
    for (int li = 0; li < 64; ++li) {
        int sw2 = (li & 7) << 3;
        bf16x8 af[4];
        #pragma unroll
        for (int kt = 0; kt < 4; ++kt) {
            u32x4 fv = *(const u32x4*)&s_fp[li * 128 + ((kt * 32 + quad * 8) ^ sw2)];
            u32x4 av;
            av.x = pk2(qpreg[kt][1] * hi2f(fv.x), qpreg[kt][0] * lo2f(fv.x));
            av.y = pk2(qpreg[kt][3] * hi2f(fv.y), qpreg[kt][2] * lo2f(fv.y));
            av.z = pk2(qpreg[kt][5] * hi2f(fv.z), qpreg[kt][4] * lo2f(fv.z));
            av.w = pk2(qpreg[kt][7] * hi2f(fv.w), qpreg[kt][6] * lo2f(fv.w));
            af[kt] = __builtin_bit_cast(bf16x8, av);
        }
        #pragma unroll
        for (int vt = 0; vt < 4; ++vt) {
            float fa = us2f(s_fa[li * 72 + vt * 16 + m]);
            f32x4 acc = (f32x4){fa, fa, fa, fa};
            #pragma unroll
            for (int kt = 0; kt < 4; ++kt)
                acc = __builtin_amdgcn_mfma_f32_16x16x32_bf16(af[kt], w3f[vt][kt], acc, 0, 0, 0);
            #pragma unroll
            for (int r = 0; r < 4; ++r) mx[vt][r] = fmaxf(mx[vt][r], acc[r]);
        }
    }

    // ---------- P4: gate / e2 epilogue (in-wave; no cross-wave max) ----------
    {
        float gwv[4], vwv[4];
        #pragma unroll
        for (int vt = 0; vt < 4; ++vt) {
            gwv[vt] = LD<BF>(gatew, vt * 16 + m);
            vwv[vt] = LD<BF>(valw, vt * 16 + m);
        }
        #pragma unroll
        for (int r = 0; r < 4; ++r) {
            float gp = 0.f, ep = 0.f;
            #pragma unroll
            for (int vt = 0; vt < 4; ++vt) {
                float qf = mx[vt][r] + qat[vt][r];
                gp += qf * gwv[vt];
                ep += qf * vwv[vt];
            }
            #pragma unroll
            for (int off = 1; off <= 8; off <<= 1) {
                gp += __shfl_xor(gp, off, 64);
                ep += __shfl_xor(ep, off, 64);
            }
            if (m == 0) {
                int gq = w * 16 + quad * 4 + r;
                float qm = LD<BF>(qmask, b * 128 + gq);
                float g = (1.0f / (1.0f + expf(-gp))) * qm;
                ST<BF>(out, OUT_QFGATE + bwf * LQ_ + gq, g);
                s_e2[gq] = expf(ep) * qm;
            }
        }
    }

    // ---------- P8: query-projection export (4 designated blocks) ----------
    if ((bwf & 15) == 0) {
        #pragma unroll
        for (int it = 0; it < 32; ++it) {
            int i = t + 512 * it;
            int row = i >> 7, col = i & 127;
            float v = us2f(s_qp[row * 128 + (col ^ ((row & 7) << 3))]);
            ST<BF>(out, OUT_QUERY + (b * 128 + row) * 128 + col, v);
        }
    }

    // ---------- P5: fragment self-attention + frag_code ----------
    if (t < 128) s_saw[t] = LD<BF>(saW, ((bwf >> 3) & 1) * 128 + t);
    __syncthreads();
    {
        int l = t >> 3, j8 = t & 7;
        int swz = (l & 7) << 3;
        float p = 0.f;
        #pragma unroll
        for (int seg = 0; seg < 2; ++seg) {
            int koff = j8 * 16 + seg * 8;
            u32x4 fv = *(const u32x4*)&s_fp[l * 128 + (koff ^ swz)];
            const float* swp = &s_saw[koff];
            p += lo2f(fv.x) * swp[0] + hi2f(fv.x) * swp[1]
               + lo2f(fv.y) * swp[2] + hi2f(fv.y) * swp[3]
               + lo2f(fv.z) * swp[4] + hi2f(fv.z) * swp[5]
               + lo2f(fv.w) * swp[6] + hi2f(fv.w) * swp[7];
        }
        p += __shfl_xor(p, 1, 64);
        p += __shfl_xor(p, 2, 64);
        p += __shfl_xor(p, 4, 64);
        if (j8 == 0) s_att[l] = expf(p) * LD<BF>(fmask, bwf * LF_ + l);
    }
    __syncthreads();
    if (t < 64) {
        float e = s_att[t], s = e;
        #pragma unroll
        for (int off = 1; off <= 32; off <<= 1) s += __shfl_xor(s, off, 64);
        float nrm = e / (s + 1e-7f);
        s_att[t] = nrm;
        ST<BF>(out, OUT_SELFATT + bwf * LF_ + t, nrm);
    }
    __syncthreads();
    {
        int d = t & 127, grp = t >> 7;
        float fc = 0.f;
        #pragma unroll
        for (int li2 = 0; li2 < 16; ++li2) {
            int l2 = grp * 16 + li2;
            fc += us2f(s_fp[l2 * 128 + (d ^ ((l2 & 7) << 3))]) * s_att[l2];
        }
        s_red[grp * 128 + d] = fc;
    }
    __syncthreads();
    if (t < 128)
        ST<BF>(out, OUT_FRAGCODE + bwf * D_ + t,
               s_red[t] + s_red[128 + t] + s_red[256 + t] + s_red[384 + t]);

    // ---------- P6: e2 softmax over the 128 q ----------
    float e2v = 0.f;
    if (t < 128) {
        e2v = s_e2[t];
        float s = e2v;
        #pragma unroll
        for (int off = 1; off <= 32; off <<= 1) s += __shfl_xor(s, off, 64);
        if (lane == 0) s_part[w] = s;
    }
    __syncthreads();
    if (t < 128) {
        float tot = s_part[0] + s_part[1] + 1e-7f;
        s_n[t] = e2v / tot;
    }
    __syncthreads();

    // ---------- P7: query_code ----------
    {
        int d = t & 127, qg = t >> 7;
        float qc = 0.f;
        #pragma unroll
        for (int qi = 0; qi < 32; ++qi) {
            int q = qg * 32 + qi;
            qc += us2f(s_qp[q * 128 + (d ^ ((q & 7) << 3))]) * s_n[q];
        }
        s_red[qg * 128 + d] = qc;
    }
    __syncthreads();
    if (t < 128)
        ST<BF>(out, OUT_QUERYCODE + bwf * D_ + t,
               s_red[t] + s_red[128 + t] + s_red[256 + t] + s_red[384 + t]);
}

__global__ __launch_bounds__(512, 2) void k_main(
    const void* query, const void* fragment, const void* qmask, const void* fmask,
    const void* projW, const void* projB, const void* saW, const void* qattW,
    const void* fattW, const void* qfW, const void* gatew, const void* valw,
    void* out)
{
    __shared__ char smem[L_TOT];
    if (is_bf(qmask))
        main_body<true >(query, fragment, qmask, fmask, projW, projB, saW, qattW,
                         fattW, qfW, gatew, valw, out, smem);
    else
        main_body<false>(query, fragment, qmask, fmask, projW, projB, saW, qattW,
                         fattW, qfW, gatew, valw, out, smem);
}

extern "C" void kernel_launch(void* const* d_in, const int* in_sizes, int n_in,
                              void* d_out, int out_size, void* d_ws, size_t ws_size,
                              hipStream_t stream)
{
    hipLaunchKernelGGL(k_main, dim3(B_ * NWF_), dim3(512), 0, stream,
                       d_in[0], d_in[1], d_in[2], d_in[3], d_in[4], d_in[5],
                       d_in[6], d_in[7], d_in[8], d_in[9], d_in[10], d_in[11],
                       d_out);
}

// Round 8
// 111.832 us; speedup vs baseline: 1.1177x; 1.1177x over previous
//
#include <hip/hip_runtime.h>
#include <hip/hip_bf16.h>

#define B_   4
#define LQ_  128
#define LF_  64
#define NW_  2
#define NFR_ 8
#define E_   128
#define D_   128
#define V_   64
#define NWF_ (NW_*NFR_)            // 16

using bf16 = __hip_bfloat16;
typedef unsigned short u16;
typedef unsigned int   u32;
typedef __attribute__((ext_vector_type(8))) short  bf16x8;
typedef __attribute__((ext_vector_type(4))) float  f32x4;
typedef __attribute__((ext_vector_type(4))) u32    u32x4;

// ---- ws layout (float-index units) ----
#define WS_PWT   0        // [128][128] u16 projW^T   8192 f
#define WS_QAT   8192     // [64][128] u16 qattW^T    4096 f
#define WS_W3T   12288    // [64][128] u16 qfW^T      4096 f
#define WS_WFT   16384    // [64][128] u16 fattW^T    4096 f
#define WS_E2    20480    // [64][128] f32            8192 f
#define WS_QPB   28672    // [4][128][128] u16       32768 f

// ---- out layout (element units; u16 if BF out else f32) ----
#define OUT_FRAGCODE  0       // (B,NW,NFR,D)   8192
#define OUT_QUERYCODE 8192    // (B,NW,NFR,D)   8192
#define OUT_SELFATT   16384   // (B,NW,NFR,LF)  4096
#define OUT_QFGATE    20480   // (B,16,LQ)      8192
#define OUT_QUERY     28672   // (B,LQ,D)       65536

// ---- k_main LDS layout (bytes) ----
#define L_FP   0        // u16 [64][128] swizzled    16384
#define L_QP   16384    // u16 [32][128] swizzled     8192
#define L_FA   24576    // u16 [64][72] fa / pmax     9216
#define L_QAT  33792    // u16 [32][72]               4608
#define L_SAW  38400    // f32 [128]                   512
#define L_ATT  38912    // f32 [64]                    256
#define L_RED  39168    // f32 [512]                  2048
#define L_TOT  41216

__device__ __forceinline__ float us2f(u16 v) { return __uint_as_float((u32)v << 16); }
__device__ __forceinline__ float lo2f(u32 v) { return __uint_as_float(v << 16); }
__device__ __forceinline__ float hi2f(u32 v) { return __uint_as_float(v & 0xffff0000u); }
__device__ __forceinline__ u16 f2b_raw(float f) {
    u32 u = __float_as_uint(f);
    return (u16)((u + 0x7fffu + ((u >> 16) & 1u)) >> 16);
}
__device__ __forceinline__ u32 pk2(float hi, float lo) {
    return __builtin_amdgcn_perm(__float_as_uint(hi), __float_as_uint(lo), 0x07060302u);
}
template<bool BF> __device__ __forceinline__ float LD(const void* p, int i) {
    return BF ? us2f(((const u16*)p)[i]) : ((const float*)p)[i];
}
template<bool BF> __device__ __forceinline__ void ST(void* p, int i, float v) {
    if (BF) ((u16*)p)[i] = f2b_raw(v); else ((float*)p)[i] = v;
}
template<bool BF> __device__ __forceinline__ u16 LDB(const void* p, int i) {
    return BF ? ((const u16*)p)[i] : f2b_raw(((const float*)p)[i]);
}
__device__ __forceinline__ bool is_bf(const void* qmask) {
    return ((const u16*)qmask)[0] == 0x3F80u;
}
// A-fragment (16 rows x 32 k) direct from global row-major [*,128]
template<bool BF>
__device__ __forceinline__ bf16x8 loadA(const void* x, int row, int kt, int quad) {
    int off = row * 128 + kt * 32 + quad * 8;
    if (BF) return *(const bf16x8*)((const u16*)x + off);
    f32x4 a = *(const f32x4*)((const float*)x + off);
    f32x4 c = *(const f32x4*)((const float*)x + off + 4);
    u32x4 av;
    av.x = pk2(a.y, a.x); av.y = pk2(a.w, a.z);
    av.z = pk2(c.y, c.x); av.w = pk2(c.w, c.z);
    return __builtin_bit_cast(bf16x8, av);
}

// ============ k_prep: 16 blocks, transpose weights to [n][k] bf16 ==========
template<bool BF>
__device__ __forceinline__ void prep_body(const void* src, u16* dst, u16* stg,
                                          int N, int k0)
{
    int t = threadIdx.x, st = N + 1, total = 32 * N;
    for (int i = t; i < total; i += 256) {
        int k = i / N, v = i % N;   // N is 64 or 128
        stg[k * st + v] = LDB<BF>(src, (k0 + k) * N + v);
    }
    __syncthreads();
    for (int j = t; j < total; j += 256) {
        int n = j >> 5, kk = j & 31;
        dst[n * 128 + k0 + kk] = stg[kk * st + n];
    }
}
__global__ __launch_bounds__(256) void k_prep(
    const void* projW, const void* qattW, const void* qfW, const void* fattW,
    const void* qmask, float* ws)
{
    __shared__ u16 stg[32 * 129];
    int mat = blockIdx.x >> 2, kq = blockIdx.x & 3;
    const void* src = (mat == 0) ? projW : (mat == 1) ? qattW : (mat == 2) ? qfW : fattW;
    u16* dst = (u16*)(ws + ((mat == 0) ? WS_PWT : (mat == 1) ? WS_QAT : (mat == 2) ? WS_W3T : WS_WFT));
    int N = (mat == 0) ? 128 : 64;
    if (is_bf(qmask)) prep_body<true >(src, dst, stg, N, kq * 32);
    else              prep_body<false>(src, dst, stg, N, kq * 32);
}

// ============ k_main: 256 blocks (bwf, qt of 32 q) x 512 thr ===============
template<bool BF>
__device__ __forceinline__ void main_body(
    const void* query, const void* fragment, const void* qmask, const void* fmask,
    const void* projB, const void* saW, const void* gatew, const void* valw,
    float* ws, void* out, char* smem)
{
    u16*   s_fp  = (u16*)(smem + L_FP);
    u16*   s_qp  = (u16*)(smem + L_QP);
    u16*   s_fa  = (u16*)(smem + L_FA);
    u16*   s_qat = (u16*)(smem + L_QAT);
    float* s_saw = (float*)(smem + L_SAW);
    float* s_att = (float*)(smem + L_ATT);
    float* s_red = (float*)(smem + L_RED);

    int bx = blockIdx.x;
    int bwf = bx >> 2, qt = bx & 3, b = bwf >> 4;
    int t = threadIdx.x, lane = t & 63, w = t >> 6;
    int m = lane & 15, quad = lane >> 4;
    int sk = (m & 7) << 3;
    const u16* pwt = (const u16*)(ws + WS_PWT);
    const u16* qatw = (const u16*)(ws + WS_QAT);
    const u16* w3t = (const u16*)(ws + WS_W3T);
    const u16* wft = (const u16*)(ws + WS_WFT);

    // ---- Phase A: projections ----
    if (w < 4) {
        // fragment rows [w*16, w*16+16)
        bf16x8 afr[4];
        #pragma unroll
        for (int kt = 0; kt < 4; ++kt)
            afr[kt] = loadA<BF>(fragment, bwf * 64 + w * 16 + m, kt, quad);
        #pragma unroll
        for (int nt = 0; nt < 8; ++nt) {
            int n = nt * 16 + m;
            float bv = LD<BF>(projB, n);
            f32x4 acc = (f32x4){bv, bv, bv, bv};
            #pragma unroll
            for (int kt = 0; kt < 4; ++kt) {
                bf16x8 bw = *(const bf16x8*)(pwt + n * 128 + kt * 32 + quad * 8);
                acc = __builtin_amdgcn_mfma_f32_16x16x32_bf16(afr[kt], bw, acc, 0, 0, 0);
            }
            #pragma unroll
            for (int rr = 0; rr < 4; ++rr) {
                int row = w * 16 + quad * 4 + rr;
                s_fp[row * 128 + (n ^ ((row & 7) << 3))] = f2b_raw(acc[rr]);
            }
        }
    } else if (w < 6) {
        // query rows qt*32 + (w-4)*16 + [0,16)
        int q0 = (w - 4) * 16;
        bf16x8 afq[4];
        #pragma unroll
        for (int kt = 0; kt < 4; ++kt)
            afq[kt] = loadA<BF>(query, b * 128 + qt * 32 + q0 + m, kt, quad);
        #pragma unroll
        for (int nt = 0; nt < 8; ++nt) {
            int n = nt * 16 + m;
            float bv = LD<BF>(projB, n);
            f32x4 acc = (f32x4){bv, bv, bv, bv};
            #pragma unroll
            for (int kt = 0; kt < 4; ++kt) {
                bf16x8 bw = *(const bf16x8*)(pwt + n * 128 + kt * 32 + quad * 8);
                acc = __builtin_amdgcn_mfma_f32_16x16x32_bf16(afq[kt], bw, acc, 0, 0, 0);
            }
            #pragma unroll
            for (int rr = 0; rr < 4; ++rr) {
                int row = q0 + quad * 4 + rr;
                s_qp[row * 128 + (n ^ ((row & 7) << 3))] = f2b_raw(acc[rr]);
            }
        }
    }
    __syncthreads();

    // ---- Phase B: f_att (waves 0-3) and q_att (waves 4-5) ----
    if (w < 4) {
        bf16x8 afa[4];
        #pragma unroll
        for (int kt = 0; kt < 4; ++kt)
            afa[kt] = *(const bf16x8*)&s_fp[(w * 16 + m) * 128 + ((kt * 32 + quad * 8) ^ sk)];
        #pragma unroll
        for (int vt = 0; vt < 4; ++vt) {
            f32x4 a0 = (f32x4){0.f, 0.f, 0.f, 0.f};
            #pragma unroll
            for (int kt = 0; kt < 4; ++kt) {
                bf16x8 wk = *(const bf16x8*)(wft + (vt * 16 + m) * 128 + kt * 32 + quad * 8);
                a0 = __builtin_amdgcn_mfma_f32_16x16x32_bf16(afa[kt], wk, a0, 0, 0, 0);
            }
            #pragma unroll
            for (int r = 0; r < 4; ++r)
                s_fa[(w * 16 + quad * 4 + r) * 72 + vt * 16 + m] = f2b_raw(a0[r]);
        }
    } else if (w < 6) {
        int q0 = (w - 4) * 16;
        bf16x8 aq[4];
        #pragma unroll
        for (int kt = 0; kt < 4; ++kt)
            aq[kt] = *(const bf16x8*)&s_qp[(q0 + m) * 128 + ((kt * 32 + quad * 8) ^ sk)];
        #pragma unroll
        for (int vt = 0; vt < 4; ++vt) {
            f32x4 a0 = (f32x4){0.f, 0.f, 0.f, 0.f};
            #pragma unroll
            for (int kt = 0; kt < 4; ++kt) {
                bf16x8 bk = *(const bf16x8*)(qatw + (vt * 16 + m) * 128 + kt * 32 + quad * 8);
                a0 = __builtin_amdgcn_mfma_f32_16x16x32_bf16(aq[kt], bk, a0, 0, 0, 0);
            }
            #pragma unroll
            for (int r = 0; r < 4; ++r)
                s_qat[(q0 + quad * 4 + r) * 72 + vt * 16 + m] = f2b_raw(a0[r]);
        }
    }
    __syncthreads();

    // ---- Phase C: l-loop. wave = (qsub, lhalf, vhalf) -> 16q x 32l x 2vt ----
    int qsub = w & 1, lhalf = (w >> 1) & 1, vhalf = (w >> 2) & 1;
    bf16x8 w3f[2][4];
    #pragma unroll
    for (int i = 0; i < 2; ++i)
        #pragma unroll
        for (int kt = 0; kt < 4; ++kt)
            w3f[i][kt] = *(const bf16x8*)(w3t + ((vhalf * 2 + i) * 16 + m) * 128 + kt * 32 + quad * 8);
    float qpreg[4][8];
    {
        #pragma unroll
        for (int kt = 0; kt < 4; ++kt) {
            bf16x8 aq2 = *(const bf16x8*)&s_qp[(qsub * 16 + m) * 128 + ((kt * 32 + quad * 8) ^ sk)];
            u32x4 uv = __builtin_bit_cast(u32x4, aq2);
            qpreg[kt][0] = lo2f(uv.x); qpreg[kt][1] = hi2f(uv.x);
            qpreg[kt][2] = lo2f(uv.y); qpreg[kt][3] = hi2f(uv.y);
            qpreg[kt][4] = lo2f(uv.z); qpreg[kt][5] = hi2f(uv.z);
            qpreg[kt][6] = lo2f(uv.w); qpreg[kt][7] = hi2f(uv.w);
        }
    }
    float mx[2][4];
    #pragma unroll
    for (int i = 0; i < 2; ++i)
        #pragma unroll
        for (int r = 0; r < 4; ++r) mx[i][r] = -1e30f;

    int lbase = lhalf * 32;
    #pragma unroll 2
    for (int li = 0; li < 32; ++li) {
        int l = lbase + li;
        int sw = (l & 7) << 3;
        bf16x8 af[4];
        #pragma unroll
        for (int kt = 0; kt < 4; ++kt) {
            u32x4 fv = *(const u32x4*)&s_fp[l * 128 + ((kt * 32 + quad * 8) ^ sw)];
            u32x4 av;
            av.x = pk2(qpreg[kt][1] * hi2f(fv.x), qpreg[kt][0] * lo2f(fv.x));
            av.y = pk2(qpreg[kt][3] * hi2f(fv.y), qpreg[kt][2] * lo2f(fv.y));
            av.z = pk2(qpreg[kt][5] * hi2f(fv.z), qpreg[kt][4] * lo2f(fv.z));
            av.w = pk2(qpreg[kt][7] * hi2f(fv.w), qpreg[kt][6] * lo2f(fv.w));
            af[kt] = __builtin_bit_cast(bf16x8, av);
        }
        #pragma unroll
        for (int i = 0; i < 2; ++i) {
            float fa = us2f(s_fa[l * 72 + (vhalf * 2 + i) * 16 + m]);
            f32x4 acc = (f32x4){fa, fa, fa, fa};
            #pragma unroll
            for (int kt = 0; kt < 4; ++kt)
                acc = __builtin_amdgcn_mfma_f32_16x16x32_bf16(af[kt], w3f[i][kt], acc, 0, 0, 0);
            #pragma unroll
            for (int r = 0; r < 4; ++r) mx[i][r] = fmaxf(mx[i][r], acc[r]);
        }
    }
    __syncthreads();   // all fa reads done
    // pmax overlay on s_fa: row = lhalf*32 + local q, col = v
    #pragma unroll
    for (int i = 0; i < 2; ++i)
        #pragma unroll
        for (int r = 0; r < 4; ++r)
            s_fa[(lhalf * 32 + qsub * 16 + quad * 4 + r) * 72 + (vhalf * 2 + i) * 16 + m] = f2b_raw(mx[i][r]);
    __syncthreads();

    // ---- Phase D: gate / e2 epilogue (q = t>>4 in [0,32), vg = t&15) ----
    {
        int q = t >> 4, vg = t & 15;
        int gq = qt * 32 + q;
        float gp = 0.f, ep = 0.f;
        #pragma unroll
        for (int jj = 0; jj < 4; ++jj) {
            int v = vg * 4 + jj;
            float mval = fmaxf(us2f(s_fa[q * 72 + v]), us2f(s_fa[(32 + q) * 72 + v]));
            float qf = mval + us2f(s_qat[q * 72 + v]);
            gp += qf * LD<BF>(gatew, v);
            ep += qf * LD<BF>(valw, v);
        }
        #pragma unroll
        for (int off = 1; off <= 8; off <<= 1) {
            gp += __shfl_xor(gp, off, 64);
            ep += __shfl_xor(ep, off, 64);
        }
        if (vg == 0) {
            float qm = LD<BF>(qmask, b * 128 + gq);
            float g = (1.0f / (1.0f + expf(-gp))) * qm;
            ST<BF>(out, OUT_QFGATE + bwf * LQ_ + gq, g);
            ws[WS_E2 + bwf * 128 + gq] = expf(ep) * qm;
        }
    }

    // ---- qp export (blocks with bwf%16==0): 32 rows -> OUT_QUERY + ws_qpb ----
    if ((bwf & 15) == 0) {
        u16* qpb = (u16*)(ws + WS_QPB);
        #pragma unroll
        for (int it = 0; it < 8; ++it) {
            int i = t + 512 * it;              // 4096 = 32*128
            int row = i >> 7, col = i & 127;
            u16 raw = s_qp[row * 128 + (col ^ ((row & 7) << 3))];
            int gr = b * 128 + qt * 32 + row;
            ST<BF>(out, OUT_QUERY + gr * 128 + col, us2f(raw));
            qpb[gr * 128 + col] = raw;
        }
    }

    // ---- fragment self-attention + frag_code (qt==0 blocks) ----
    if (qt == 0) {
        if (t < 128) s_saw[t] = LD<BF>(saW, ((bwf >> 3) & 1) * 128 + t);
        __syncthreads();
        {
            int l = t >> 3, j8 = t & 7;
            int swz = (l & 7) << 3;
            float p = 0.f;
            #pragma unroll
            for (int seg = 0; seg < 2; ++seg) {
                int koff = j8 * 16 + seg * 8;
                u32x4 fv = *(const u32x4*)&s_fp[l * 128 + (koff ^ swz)];
                const float* swp = &s_saw[koff];
                p += lo2f(fv.x) * swp[0] + hi2f(fv.x) * swp[1]
                   + lo2f(fv.y) * swp[2] + hi2f(fv.y) * swp[3]
                   + lo2f(fv.z) * swp[4] + hi2f(fv.z) * swp[5]
                   + lo2f(fv.w) * swp[6] + hi2f(fv.w) * swp[7];
            }
            p += __shfl_xor(p, 1, 64);
            p += __shfl_xor(p, 2, 64);
            p += __shfl_xor(p, 4, 64);
            if (j8 == 0) s_att[l] = expf(p) * LD<BF>(fmask, bwf * LF_ + l);
        }
        __syncthreads();
        if (t < 64) {
            float e = s_att[t], s = e;
            #pragma unroll
            for (int off = 1; off <= 32; off <<= 1) s += __shfl_xor(s, off, 64);
            float nrm = e / (s + 1e-7f);
            s_att[t] = nrm;
            ST<BF>(out, OUT_SELFATT + bwf * LF_ + t, nrm);
        }
        __syncthreads();
        {
            int d = t & 127, grp = t >> 7;
            float fc = 0.f;
            #pragma unroll
            for (int li2 = 0; li2 < 16; ++li2) {
                int l2 = grp * 16 + li2;
                fc += us2f(s_fp[l2 * 128 + (d ^ ((l2 & 7) << 3))]) * s_att[l2];
            }
            s_red[grp * 128 + d] = fc;
        }
        __syncthreads();
        if (t < 128)
            ST<BF>(out, OUT_FRAGCODE + bwf * D_ + t,
                   s_red[t] + s_red[128 + t] + s_red[256 + t] + s_red[384 + t]);
    }
}
__global__ __launch_bounds__(512, 4) void k_main(
    const void* query, const void* fragment, const void* qmask, const void* fmask,
    const void* projB, const void* saW, const void* gatew, const void* valw,
    float* ws, void* out)
{
    __shared__ char smem[L_TOT];
    if (is_bf(qmask))
        main_body<true >(query, fragment, qmask, fmask, projB, saW, gatew, valw, ws, out, smem);
    else
        main_body<false>(query, fragment, qmask, fmask, projB, saW, gatew, valw, ws, out, smem);
}

// ============ k_qcode: 64 blocks x 128 thr =================================
template<bool BF>
__device__ __forceinline__ void qcode_body(const float* ws, void* out,
                                           u16* s_q, float* s_n, float* s_part)
{
    int bwf = blockIdx.x, b = bwf >> 4, t = threadIdx.x;
    // stage qp for this b (128x128 bf16 = 8192 u32) coalesced
    {
        const u32* src = (const u32*)((const u16*)(ws + WS_QPB) + (size_t)b * 16384);
        u32* dst = (u32*)s_q;
        #pragma unroll
        for (int it = 0; it < 64; ++it) dst[t + 128 * it] = src[t + 128 * it];
    }
    float e = ws[WS_E2 + bwf * 128 + t];
    float s = e;
    #pragma unroll
    for (int off = 1; off <= 32; off <<= 1) s += __shfl_xor(s, off, 64);
    if ((t & 63) == 0) s_part[t >> 6] = s;
    __syncthreads();
    float tot = s_part[0] + s_part[1] + 1e-7f;
    s_n[t] = e / tot;
    __syncthreads();
    float qc = 0.f;
    #pragma unroll 8
    for (int q = 0; q < 128; ++q)
        qc += us2f(s_q[q * 128 + t]) * s_n[q];
    ST<BF>(out, OUT_QUERYCODE + bwf * D_ + t, qc);
}
__global__ __launch_bounds__(128) void k_qcode(const void* qmask, const float* ws, void* out)
{
    __shared__ u16 s_q[128 * 128];
    __shared__ float s_n[128];
    __shared__ float s_part[2];
    if (is_bf(qmask)) qcode_body<true >(ws, out, s_q, s_n, s_part);
    else              qcode_body<false>(ws, out, s_q, s_n, s_part);
}

extern "C" void kernel_launch(void* const* d_in, const int* in_sizes, int n_in,
                              void* d_out, int out_size, void* d_ws, size_t ws_size,
                              hipStream_t stream)
{
    const void* query    = d_in[0];
    const void* fragment = d_in[1];
    const void* qmask    = d_in[2];
    const void* fmask    = d_in[3];
    const void* projW    = d_in[4];
    const void* projB    = d_in[5];
    const void* saW      = d_in[6];
    const void* qattW    = d_in[7];
    const void* fattW    = d_in[8];
    const void* qfW      = d_in[9];
    const void* gatew    = d_in[10];
    const void* valw     = d_in[11];
    float* ws = (float*)d_ws;

    hipLaunchKernelGGL(k_prep, dim3(16), dim3(256), 0, stream,
                       projW, qattW, qfW, fattW, qmask, ws);
    hipLaunchKernelGGL(k_main, dim3(256), dim3(512), 0, stream,
                       query, fragment, qmask, fmask, projB, saW, gatew, valw, ws, d_out);
    hipLaunchKernelGGL(k_qcode, dim3(B_ * NWF_), dim3(128), 0, stream,
                       qmask, ws, d_out);
}

// Round 9
// 110.855 us; speedup vs baseline: 1.1275x; 1.0088x over previous
//
#include <hip/hip_runtime.h>
#include <hip/hip_bf16.h>

#define B_   4
#define LQ_  128
#define LF_  64
#define NW_  2
#define NFR_ 8
#define E_   128
#define D_   128
#define V_   64
#define NWF_ (NW_*NFR_)            // 16

using bf16 = __hip_bfloat16;
typedef unsigned short u16;
typedef unsigned int   u32;
typedef __attribute__((ext_vector_type(8))) short  bf16x8;
typedef __attribute__((ext_vector_type(4))) float  f32x4;
typedef __attribute__((ext_vector_type(4))) u32    u32x4;

// ---- ws layout (float-index units) ----
#define WS_PWT   0        // [128][128] u16 projW^T   8192 f
#define WS_QAT   8192     // [64][128] u16 qattW^T    4096 f
#define WS_W3T   12288    // [64][128] u16 qfW^T      4096 f
#define WS_WFT   16384    // [64][128] u16 fattW^T    4096 f
#define WS_E2    20480    // [64][128] f32            8192 f
#define WS_QPB   28672    // [4][128][128] u16       32768 f

// ---- out layout (element units; u16 if BF out else f32) ----
#define OUT_FRAGCODE  0       // (B,NW,NFR,D)   8192
#define OUT_QUERYCODE 8192    // (B,NW,NFR,D)   8192
#define OUT_SELFATT   16384   // (B,NW,NFR,LF)  4096
#define OUT_QFGATE    20480   // (B,16,LQ)      8192
#define OUT_QUERY     28672   // (B,LQ,D)       65536

// ---- k_main LDS layout (bytes) ----
#define L_FP   0        // u16 [64][128] swizzled    16384
#define L_QP   16384    // u16 [32][128] swizzled     8192
#define L_FA   24576    // u16 [64][72] fa / pmax     9216
#define L_QAT  33792    // u16 [32][72]               4608
#define L_SAW  38400    // f32 [128]                   512
#define L_ATT  38912    // f32 [64]                    256
#define L_RED  39168    // f32 [512]                  2048
#define L_TOT  41216

__device__ __forceinline__ float us2f(u16 v) { return __uint_as_float((u32)v << 16); }
__device__ __forceinline__ float lo2f(u32 v) { return __uint_as_float(v << 16); }
__device__ __forceinline__ float hi2f(u32 v) { return __uint_as_float(v & 0xffff0000u); }
__device__ __forceinline__ u16 f2b_raw(float f) {
    u32 u = __float_as_uint(f);
    return (u16)((u + 0x7fffu + ((u >> 16) & 1u)) >> 16);
}
__device__ __forceinline__ u32 pk2(float hi, float lo) {
    return __builtin_amdgcn_perm(__float_as_uint(hi), __float_as_uint(lo), 0x07060302u);
}
template<bool BF> __device__ __forceinline__ float LD(const void* p, int i) {
    return BF ? us2f(((const u16*)p)[i]) : ((const float*)p)[i];
}
template<bool BF> __device__ __forceinline__ void ST(void* p, int i, float v) {
    if (BF) ((u16*)p)[i] = f2b_raw(v); else ((float*)p)[i] = v;
}
template<bool BF> __device__ __forceinline__ u16 LDB(const void* p, int i) {
    return BF ? ((const u16*)p)[i] : f2b_raw(((const float*)p)[i]);
}
__device__ __forceinline__ bool is_bf(const void* qmask) {
    return ((const u16*)qmask)[0] == 0x3F80u;
}
// A-fragment (16 rows x 32 k) direct from global row-major [*,128]
template<bool BF>
__device__ __forceinline__ bf16x8 loadA(const void* x, int row, int kt, int quad) {
    int off = row * 128 + kt * 32 + quad * 8;
    if (BF) return *(const bf16x8*)((const u16*)x + off);
    f32x4 a = *(const f32x4*)((const float*)x + off);
    f32x4 c = *(const f32x4*)((const float*)x + off + 4);
    u32x4 av;
    av.x = pk2(a.y, a.x); av.y = pk2(a.w, a.z);
    av.z = pk2(c.y, c.x); av.w = pk2(c.w, c.z);
    return __builtin_bit_cast(bf16x8, av);
}

// ============ k_prep: 16 blocks, transpose weights to [n][k] bf16 ==========
template<bool BF>
__device__ __forceinline__ void prep_body(const void* src, u16* dst, u16* stg,
                                          int N, int k0)
{
    int t = threadIdx.x, st = N + 1, total = 32 * N;
    for (int i = t; i < total; i += 256) {
        int k = i / N, v = i % N;   // N is 64 or 128
        stg[k * st + v] = LDB<BF>(src, (k0 + k) * N + v);
    }
    __syncthreads();
    for (int j = t; j < total; j += 256) {
        int n = j >> 5, kk = j & 31;
        dst[n * 128 + k0 + kk] = stg[kk * st + n];
    }
}
__global__ __launch_bounds__(256) void k_prep(
    const void* projW, const void* qattW, const void* qfW, const void* fattW,
    const void* qmask, float* ws)
{
    __shared__ u16 stg[32 * 129];
    int mat = blockIdx.x >> 2, kq = blockIdx.x & 3;
    const void* src = (mat == 0) ? projW : (mat == 1) ? qattW : (mat == 2) ? qfW : fattW;
    u16* dst = (u16*)(ws + ((mat == 0) ? WS_PWT : (mat == 1) ? WS_QAT : (mat == 2) ? WS_W3T : WS_WFT));
    int N = (mat == 0) ? 128 : 64;
    if (is_bf(qmask)) prep_body<true >(src, dst, stg, N, kq * 32);
    else              prep_body<false>(src, dst, stg, N, kq * 32);
}

// ============ k_main: 256 blocks (qt, bwf) x 512 thr =======================
// XCD-spread decode: qt = bx>>6 (4 groups of 64), bwf = bx&63 -> the heavy
// epilogue blocks (fragatt: qt == bwf&3) and export blocks (bwf&15==0) are
// distributed evenly across the 8 XCDs instead of clustering on XCD 0/4.
template<bool BF>
__device__ __forceinline__ void main_body(
    const void* query, const void* fragment, const void* qmask, const void* fmask,
    const void* projB, const void* saW, const void* gatew, const void* valw,
    float* ws, void* out, char* smem)
{
    u16*   s_fp  = (u16*)(smem + L_FP);
    u16*   s_qp  = (u16*)(smem + L_QP);
    u16*   s_fa  = (u16*)(smem + L_FA);
    u16*   s_qat = (u16*)(smem + L_QAT);
    float* s_saw = (float*)(smem + L_SAW);
    float* s_att = (float*)(smem + L_ATT);
    float* s_red = (float*)(smem + L_RED);

    int bx = blockIdx.x;
    int qt = bx >> 6, bwf = bx & 63, b = bwf >> 4;
    int t = threadIdx.x, lane = t & 63, w = t >> 6;
    int m = lane & 15, quad = lane >> 4;
    int sk = (m & 7) << 3;
    const u16* pwt = (const u16*)(ws + WS_PWT);
    const u16* qatw = (const u16*)(ws + WS_QAT);
    const u16* w3t = (const u16*)(ws + WS_W3T);
    const u16* wft = (const u16*)(ws + WS_WFT);
    bool do_fragatt = (qt == (bwf & 3));
    bool do_export  = ((bwf & 15) == 0);

    // ---- Phase A: projections ----
    if (w < 4) {
        // fragment rows [w*16, w*16+16)
        bf16x8 afr[4];
        #pragma unroll
        for (int kt = 0; kt < 4; ++kt)
            afr[kt] = loadA<BF>(fragment, bwf * 64 + w * 16 + m, kt, quad);
        #pragma unroll
        for (int nt = 0; nt < 8; ++nt) {
            int n = nt * 16 + m;
            float bv = LD<BF>(projB, n);
            f32x4 acc = (f32x4){bv, bv, bv, bv};
            #pragma unroll
            for (int kt = 0; kt < 4; ++kt) {
                bf16x8 bw = *(const bf16x8*)(pwt + n * 128 + kt * 32 + quad * 8);
                acc = __builtin_amdgcn_mfma_f32_16x16x32_bf16(afr[kt], bw, acc, 0, 0, 0);
            }
            #pragma unroll
            for (int rr = 0; rr < 4; ++rr) {
                int row = w * 16 + quad * 4 + rr;
                s_fp[row * 128 + (n ^ ((row & 7) << 3))] = f2b_raw(acc[rr]);
            }
        }
    } else if (w < 6) {
        // query rows qt*32 + (w-4)*16 + [0,16)
        int q0 = (w - 4) * 16;
        bf16x8 afq[4];
        #pragma unroll
        for (int kt = 0; kt < 4; ++kt)
            afq[kt] = loadA<BF>(query, b * 128 + qt * 32 + q0 + m, kt, quad);
        #pragma unroll
        for (int nt = 0; nt < 8; ++nt) {
            int n = nt * 16 + m;
            float bv = LD<BF>(projB, n);
            f32x4 acc = (f32x4){bv, bv, bv, bv};
            #pragma unroll
            for (int kt = 0; kt < 4; ++kt) {
                bf16x8 bw = *(const bf16x8*)(pwt + n * 128 + kt * 32 + quad * 8);
                acc = __builtin_amdgcn_mfma_f32_16x16x32_bf16(afq[kt], bw, acc, 0, 0, 0);
            }
            #pragma unroll
            for (int rr = 0; rr < 4; ++rr) {
                int row = q0 + quad * 4 + rr;
                s_qp[row * 128 + (n ^ ((row & 7) << 3))] = f2b_raw(acc[rr]);
            }
        }
    }
    __syncthreads();

    // ---- Phase B: f_att (waves 0-3) and q_att (waves 4-5) ----
    if (w < 4) {
        bf16x8 afa[4];
        #pragma unroll
        for (int kt = 0; kt < 4; ++kt)
            afa[kt] = *(const bf16x8*)&s_fp[(w * 16 + m) * 128 + ((kt * 32 + quad * 8) ^ sk)];
        #pragma unroll
        for (int vt = 0; vt < 4; ++vt) {
            f32x4 a0 = (f32x4){0.f, 0.f, 0.f, 0.f};
            #pragma unroll
            for (int kt = 0; kt < 4; ++kt) {
                bf16x8 wk = *(const bf16x8*)(wft + (vt * 16 + m) * 128 + kt * 32 + quad * 8);
                a0 = __builtin_amdgcn_mfma_f32_16x16x32_bf16(afa[kt], wk, a0, 0, 0, 0);
            }
            #pragma unroll
            for (int r = 0; r < 4; ++r)
                s_fa[(w * 16 + quad * 4 + r) * 72 + vt * 16 + m] = f2b_raw(a0[r]);
        }
    } else if (w < 6) {
        int q0 = (w - 4) * 16;
        bf16x8 aq[4];
        #pragma unroll
        for (int kt = 0; kt < 4; ++kt)
            aq[kt] = *(const bf16x8*)&s_qp[(q0 + m) * 128 + ((kt * 32 + quad * 8) ^ sk)];
        #pragma unroll
        for (int vt = 0; vt < 4; ++vt) {
            f32x4 a0 = (f32x4){0.f, 0.f, 0.f, 0.f};
            #pragma unroll
            for (int kt = 0; kt < 4; ++kt) {
                bf16x8 bk = *(const bf16x8*)(qatw + (vt * 16 + m) * 128 + kt * 32 + quad * 8);
                a0 = __builtin_amdgcn_mfma_f32_16x16x32_bf16(aq[kt], bk, a0, 0, 0, 0);
            }
            #pragma unroll
            for (int r = 0; r < 4; ++r)
                s_qat[(q0 + quad * 4 + r) * 72 + vt * 16 + m] = f2b_raw(a0[r]);
        }
    }
    __syncthreads();

    // ---- Phase C: l-loop. wave = (qsub, lhalf, vhalf) -> 16q x 32l x 2vt ----
    int qsub = w & 1, lhalf = (w >> 1) & 1, vhalf = (w >> 2) & 1;
    bf16x8 w3f[2][4];
    #pragma unroll
    for (int i = 0; i < 2; ++i)
        #pragma unroll
        for (int kt = 0; kt < 4; ++kt)
            w3f[i][kt] = *(const bf16x8*)(w3t + ((vhalf * 2 + i) * 16 + m) * 128 + kt * 32 + quad * 8);
    float qpreg[4][8];
    {
        #pragma unroll
        for (int kt = 0; kt < 4; ++kt) {
            bf16x8 aq2 = *(const bf16x8*)&s_qp[(qsub * 16 + m) * 128 + ((kt * 32 + quad * 8) ^ sk)];
            u32x4 uv = __builtin_bit_cast(u32x4, aq2);
            qpreg[kt][0] = lo2f(uv.x); qpreg[kt][1] = hi2f(uv.x);
            qpreg[kt][2] = lo2f(uv.y); qpreg[kt][3] = hi2f(uv.y);
            qpreg[kt][4] = lo2f(uv.z); qpreg[kt][5] = hi2f(uv.z);
            qpreg[kt][6] = lo2f(uv.w); qpreg[kt][7] = hi2f(uv.w);
        }
    }
    float mx[2][4];
    #pragma unroll
    for (int i = 0; i < 2; ++i)
        #pragma unroll
        for (int r = 0; r < 4; ++r) mx[i][r] = -1e30f;

    int lbase = lhalf * 32;
    #pragma unroll 2
    for (int li = 0; li < 32; ++li) {
        int l = lbase + li;
        int sw = (l & 7) << 3;
        bf16x8 af[4];
        #pragma unroll
        for (int kt = 0; kt < 4; ++kt) {
            u32x4 fv = *(const u32x4*)&s_fp[l * 128 + ((kt * 32 + quad * 8) ^ sw)];
            u32x4 av;
            av.x = pk2(qpreg[kt][1] * hi2f(fv.x), qpreg[kt][0] * lo2f(fv.x));
            av.y = pk2(qpreg[kt][3] * hi2f(fv.y), qpreg[kt][2] * lo2f(fv.y));
            av.z = pk2(qpreg[kt][5] * hi2f(fv.z), qpreg[kt][4] * lo2f(fv.z));
            av.w = pk2(qpreg[kt][7] * hi2f(fv.w), qpreg[kt][6] * lo2f(fv.w));
            af[kt] = __builtin_bit_cast(bf16x8, av);
        }
        #pragma unroll
        for (int i = 0; i < 2; ++i) {
            float fa = us2f(s_fa[l * 72 + (vhalf * 2 + i) * 16 + m]);
            f32x4 acc = (f32x4){fa, fa, fa, fa};
            #pragma unroll
            for (int kt = 0; kt < 4; ++kt)
                acc = __builtin_amdgcn_mfma_f32_16x16x32_bf16(af[kt], w3f[i][kt], acc, 0, 0, 0);
            #pragma unroll
            for (int r = 0; r < 4; ++r) mx[i][r] = fmaxf(mx[i][r], acc[r]);
        }
    }
    __syncthreads();   // all fa reads done
    // pmax overlay on s_fa: row = lhalf*32 + local q, col = v
    #pragma unroll
    for (int i = 0; i < 2; ++i)
        #pragma unroll
        for (int r = 0; r < 4; ++r)
            s_fa[(lhalf * 32 + qsub * 16 + quad * 4 + r) * 72 + (vhalf * 2 + i) * 16 + m] = f2b_raw(mx[i][r]);
    __syncthreads();

    // ---- Phase D: gate / e2 epilogue (q = t>>4 in [0,32), vg = t&15) ----
    {
        int q = t >> 4, vg = t & 15;
        int gq = qt * 32 + q;
        float gp = 0.f, ep = 0.f;
        #pragma unroll
        for (int jj = 0; jj < 4; ++jj) {
            int v = vg * 4 + jj;
            float mval = fmaxf(us2f(s_fa[q * 72 + v]), us2f(s_fa[(32 + q) * 72 + v]));
            float qf = mval + us2f(s_qat[q * 72 + v]);
            gp += qf * LD<BF>(gatew, v);
            ep += qf * LD<BF>(valw, v);
        }
        #pragma unroll
        for (int off = 1; off <= 8; off <<= 1) {
            gp += __shfl_xor(gp, off, 64);
            ep += __shfl_xor(ep, off, 64);
        }
        if (vg == 0) {
            float qm = LD<BF>(qmask, b * 128 + gq);
            float g = (1.0f / (1.0f + expf(-gp))) * qm;
            ST<BF>(out, OUT_QFGATE + bwf * LQ_ + gq, g);
            ws[WS_E2 + bwf * 128 + gq] = expf(ep) * qm;
        }
    }

    // ---- qp export (bwf%16==0 blocks; each exports its own 32 q rows) ----
    if (do_export) {
        u16* qpb = (u16*)(ws + WS_QPB);
        #pragma unroll
        for (int it = 0; it < 8; ++it) {
            int i = t + 512 * it;              // 4096 = 32*128
            int row = i >> 7, col = i & 127;
            u16 raw = s_qp[row * 128 + (col ^ ((row & 7) << 3))];
            int gr = b * 128 + qt * 32 + row;
            ST<BF>(out, OUT_QUERY + gr * 128 + col, us2f(raw));
            qpb[gr * 128 + col] = raw;
        }
    }

    // ---- fragment self-attention + frag_code (XCD-spread assignment) ----
    if (do_fragatt) {
        if (t < 128) s_saw[t] = LD<BF>(saW, ((bwf >> 3) & 1) * 128 + t);
        __syncthreads();
        {
            int l = t >> 3, j8 = t & 7;
            int swz = (l & 7) << 3;
            float p = 0.f;
            #pragma unroll
            for (int seg = 0; seg < 2; ++seg) {
                int koff = j8 * 16 + seg * 8;
                u32x4 fv = *(const u32x4*)&s_fp[l * 128 + (koff ^ swz)];
                const float* swp = &s_saw[koff];
                p += lo2f(fv.x) * swp[0] + hi2f(fv.x) * swp[1]
                   + lo2f(fv.y) * swp[2] + hi2f(fv.y) * swp[3]
                   + lo2f(fv.z) * swp[4] + hi2f(fv.z) * swp[5]
                   + lo2f(fv.w) * swp[6] + hi2f(fv.w) * swp[7];
            }
            p += __shfl_xor(p, 1, 64);
            p += __shfl_xor(p, 2, 64);
            p += __shfl_xor(p, 4, 64);
            if (j8 == 0) s_att[l] = expf(p) * LD<BF>(fmask, bwf * LF_ + l);
        }
        __syncthreads();
        if (t < 64) {
            float e = s_att[t], s = e;
            #pragma unroll
            for (int off = 1; off <= 32; off <<= 1) s += __shfl_xor(s, off, 64);
            float nrm = e / (s + 1e-7f);
            s_att[t] = nrm;
            ST<BF>(out, OUT_SELFATT + bwf * LF_ + t, nrm);
        }
        __syncthreads();
        {
            int d = t & 127, grp = t >> 7;
            float fc = 0.f;
            #pragma unroll
            for (int li2 = 0; li2 < 16; ++li2) {
                int l2 = grp * 16 + li2;
                fc += us2f(s_fp[l2 * 128 + (d ^ ((l2 & 7) << 3))]) * s_att[l2];
            }
            s_red[grp * 128 + d] = fc;
        }
        __syncthreads();
        if (t < 128)
            ST<BF>(out, OUT_FRAGCODE + bwf * D_ + t,
                   s_red[t] + s_red[128 + t] + s_red[256 + t] + s_red[384 + t]);
    }
}
__global__ __launch_bounds__(512, 4) void k_main(
    const void* query, const void* fragment, const void* qmask, const void* fmask,
    const void* projB, const void* saW, const void* gatew, const void* valw,
    float* ws, void* out)
{
    __shared__ char smem[L_TOT];
    if (is_bf(qmask))
        main_body<true >(query, fragment, qmask, fmask, projB, saW, gatew, valw, ws, out, smem);
    else
        main_body<false>(query, fragment, qmask, fmask, projB, saW, gatew, valw, ws, out, smem);
}

// ============ k_qcode: 64 blocks x 128 thr =================================
template<bool BF>
__device__ __forceinline__ void qcode_body(const float* ws, void* out,
                                           u16* s_q, float* s_n, float* s_part)
{
    int bwf = blockIdx.x, b = bwf >> 4, t = threadIdx.x;
    // stage qp for this b (128x128 bf16 = 8192 u32) coalesced
    {
        const u32* src = (const u32*)((const u16*)(ws + WS_QPB) + (size_t)b * 16384);
        u32* dst = (u32*)s_q;
        #pragma unroll
        for (int it = 0; it < 64; ++it) dst[t + 128 * it] = src[t + 128 * it];
    }
    float e = ws[WS_E2 + bwf * 128 + t];
    float s = e;
    #pragma unroll
    for (int off = 1; off <= 32; off <<= 1) s += __shfl_xor(s, off, 64);
    if ((t & 63) == 0) s_part[t >> 6] = s;
    __syncthreads();
    float tot = s_part[0] + s_part[1] + 1e-7f;
    s_n[t] = e / tot;
    __syncthreads();
    float qc = 0.f;
    #pragma unroll 8
    for (int q = 0; q < 128; ++q)
        qc += us2f(s_q[q * 128 + t]) * s_n[q];
    ST<BF>(out, OUT_QUERYCODE + bwf * D_ + t, qc);
}
__global__ __launch_bounds__(128) void k_qcode(const void* qmask, const float* ws, void* out)
{
    __shared__ u16 s_q[128 * 128];
    __shared__ float s_n[128];
    __shared__ float s_part[2];
    if (is_bf(qmask)) qcode_body<true >(ws, out, s_q, s_n, s_part);
    else              qcode_body<false>(ws, out, s_q, s_n, s_part);
}

extern "C" void kernel_launch(void* const* d_in, const int* in_sizes, int n_in,
                              void* d_out, int out_size, void* d_ws, size_t ws_size,
                              hipStream_t stream)
{
    const void* query    = d_in[0];
    const void* fragment = d_in[1];
    const void* qmask    = d_in[2];
    const void* fmask    = d_in[3];
    const void* projW    = d_in[4];
    const void* projB    = d_in[5];
    const void* saW      = d_in[6];
    const void* qattW    = d_in[7];
    const void* fattW    = d_in[8];
    const void* qfW      = d_in[9];
    const void* gatew    = d_in[10];
    const void* valw     = d_in[11];
    float* ws = (float*)d_ws;

    hipLaunchKernelGGL(k_prep, dim3(16), dim3(256), 0, stream,
                       projW, qattW, qfW, fattW, qmask, ws);
    hipLaunchKernelGGL(k_main, dim3(256), dim3(512), 0, stream,
                       query, fragment, qmask, fmask, projB, saW, gatew, valw, ws, d_out);
    hipLaunchKernelGGL(k_qcode, dim3(B_ * NWF_), dim3(128), 0, stream,
                       qmask, ws, d_out);
}